// Round 2
// baseline (184.728 us; speedup 1.0000x reference)
//
#include <hip/hip_runtime.h>

#define NF 36
#define QN 100
#define TN 20
#define CN 92
#define NB 64
#define BSTR 112   // ben/price row pad; [100..111] are -INF / 0 sentinels

// top-2 scan step carrying (v0,i0,b0 | v1,i1,b1); med3 = exact second-max update
// given invariant v0 >= v1. Strict '>' keeps lowest q on ties (matches top_k).
#define SCAN6(BV, PV, IDX) do { \
    float v_ = (BV) - (PV); \
    bool c_ = v_ > v0; \
    bool d_ = v_ > v1; \
    float nv1_ = __builtin_amdgcn_fmed3f(v_, v0, v1); \
    i1 = c_ ? i0 : (d_ ? (IDX) : i1); \
    b1 = c_ ? b0 : (d_ ? (BV) : b1); \
    v1 = nv1_; \
    i0 = c_ ? (IDX) : i0; \
    b0 = c_ ? (BV) : b0; \
    v0 = fmaxf(v0, v_); } while (0)

// ordered top-2 merge: neighbor tuple is the HIGHER-q chunk (strict '>' keeps lower q on ties)
#define MERGE6(NV0, NI0, NB0, NV1, NI1, NB1) do { \
    bool t_  = (NV0) > v0; \
    bool s1_ = (NV1) > v0; \
    bool s2_ = (NV0) > v1; \
    float mv1_ = t_ ? (s1_ ? (NV1) : v0) : (s2_ ? (NV0) : v1); \
    int   mi1_ = t_ ? (s1_ ? (NI1) : i0) : (s2_ ? (NI0) : i1); \
    float mb1_ = t_ ? (s1_ ? (NB1) : b0) : (s2_ ? (NB0) : b1); \
    v0 = t_ ? (NV0) : v0; \
    i0 = t_ ? (NI0) : i0; \
    b0 = t_ ? (NB0) : b0; \
    v1 = mv1_; i1 = mi1_; b1 = mb1_; } while (0)

__global__ __launch_bounds__(64) void matcher_kernel(
    const float* __restrict__ logits,   // [64][3600][92]
    const float* __restrict__ pboxes,   // [64][3600][4]
    const int*   __restrict__ tlabels,  // [36][64][20]
    const float* __restrict__ tboxes,   // [36][64][20][4]
    float* __restrict__ out_cost,       // [64][36][100][20]
    float* __restrict__ out_pred,       // [64][36][20]
    float* __restrict__ out_tgt)        // [64][36][20]
{
    const int bf = blockIdx.x;          // b*36 + f
    const int b  = bf / NF;
    const int f  = bf % NF;
    const int lane = threadIdx.x;

    __shared__ __align__(16) float ben[TN][BSTR];   // benefit[t][q] = -cost[q][t]
    __shared__ __align__(16) float price[BSTR];
    __shared__ unsigned long long bid2[TN];         // (bidf bits << 32) | bidq
    __shared__ int   objl[TN];
    __shared__ int   slab[TN];
    __shared__ float tbr[TN][4];        // raw cxcywh
    __shared__ float tbx[TN][4];        // xyxy
    __shared__ float tarea[TN];

    // ---- stage targets ----
    if (lane < TN) {
        const int base = (f * NB + b) * TN + lane;
        slab[lane] = tlabels[base];
        const float* tb = tboxes + (size_t)base * 4;
        float cx = tb[0], cy = tb[1], w = tb[2], h = tb[3];
        tbr[lane][0] = cx; tbr[lane][1] = cy; tbr[lane][2] = w; tbr[lane][3] = h;
        float x1 = cx - 0.5f * w, y1 = cy - 0.5f * h;
        float x2 = cx + 0.5f * w, y2 = cy + 0.5f * h;
        tbx[lane][0] = x1; tbx[lane][1] = y1; tbx[lane][2] = x2; tbx[lane][3] = y2;
        tarea[lane] = (x2 - x1) * (y2 - y1);
    }
    __syncthreads();

    // ---- cost phase: register-resident logits, 2 passes over q (unchanged numerics) ----
    float mn = INFINITY, mx = -INFINITY;
    for (int p = 0; p < 2; ++p) {
        const int q = lane + 64 * p;
        if (q < QN) {
            const size_t row = (size_t)b * (NF * QN) + (size_t)f * QN + q;
            const float* L = logits + row * CN;
            const float4* L4 = reinterpret_cast<const float4*>(L);
            float4 r[23];
            #pragma unroll
            for (int i = 0; i < 23; ++i) r[i] = L4[i];
            // pin the row in VGPRs: forbid re-load for the exp pass (VGPR=60 showed spill-to-reload)
            #pragma unroll
            for (int i = 0; i < 23; ++i) {
                asm volatile("" : "+v"(r[i].x), "+v"(r[i].y), "+v"(r[i].z), "+v"(r[i].w));
            }
            float m = -INFINITY;
            #pragma unroll
            for (int i = 0; i < 23; ++i) {
                float4 v = r[i];
                m = fmaxf(m, v.x); m = fmaxf(m, v.y); m = fmaxf(m, v.z); m = fmaxf(m, v.w);
            }
            float s = 0.f;
            #pragma unroll
            for (int i = 0; i < 23; ++i) {
                float4 v = r[i];
                s += expf(v.x - m); s += expf(v.y - m); s += expf(v.z - m); s += expf(v.w - m);
            }

            float4 pbv = reinterpret_cast<const float4*>(pboxes)[row];
            float cx = pbv.x, cy = pbv.y, w = pbv.z, h = pbv.w;
            float px1 = cx - 0.5f * w, py1 = cy - 0.5f * h;
            float px2 = cx + 0.5f * w, py2 = cy + 0.5f * h;
            float a1 = (px2 - px1) * (py2 - py1);

            for (int t = 0; t < TN; ++t) {
                float pc = expf(L[slab[t]] - m) / s;   // L1/L2-warm gather
                float cb = fabsf(cx - tbr[t][0]) + fabsf(cy - tbr[t][1]);
                cb = cb + fabsf(w - tbr[t][2]);
                cb = cb + fabsf(h - tbr[t][3]);
                float ltx = fmaxf(px1, tbx[t][0]), lty = fmaxf(py1, tbx[t][1]);
                float rbx = fminf(px2, tbx[t][2]), rby = fminf(py2, tbx[t][3]);
                float wx = fmaxf(rbx - ltx, 0.f), wy = fmaxf(rby - lty, 0.f);
                float inter = wx * wy;
                float uni = a1 + tarea[t] - inter;
                float iou = inter / uni;
                float ex1 = fminf(px1, tbx[t][0]), ey1 = fminf(py1, tbx[t][1]);
                float ex2 = fmaxf(px2, tbx[t][2]), ey2 = fmaxf(py2, tbx[t][3]);
                float ew = fmaxf(ex2 - ex1, 0.f), eh = fmaxf(ey2 - ey1, 0.f);
                float ae = ew * eh;
                float giou = iou - (ae - uni) / ae;
                float cost = (-pc) + 5.0f * cb - 2.0f * giou;
                ben[t][q] = -cost;
                mn = fminf(mn, cost);
                mx = fmaxf(mx, cost);
            }
        }
    }

    // init price + sentinels
    for (int i = lane; i < BSTR; i += 64) price[i] = 0.f;
    if (lane < TN) {
        float4 ninf; ninf.x = ninf.y = ninf.z = ninf.w = -INFINITY;
        float4* sp = reinterpret_cast<float4*>(&ben[lane][100]);   // 400B offset, 16B aligned
        sp[0] = ninf; sp[1] = ninf; sp[2] = ninf;                  // q = 100..111
    }
    __syncthreads();

    // eps (exact: spread = (-mn)-(-mx)+1e-6, /1000) — min/max exact under any order
    #pragma unroll
    for (int off = 32; off > 0; off >>= 1) {
        mn = fminf(mn, __shfl_xor(mn, off, 64));
        mx = fmaxf(mx, __shfl_xor(mx, off, 64));
    }
    const float eps = (((-mn) - (-mx)) + 1e-6f) / 1000.0f;

    // coalesced cost write-out from LDS
    {
        float4* dst = reinterpret_cast<float4*>(out_cost + (size_t)bf * (QN * TN));
        for (int i = lane; i < (QN * TN) / 4; i += 64) {
            int k = i * 4;
            int q = k / TN, t0 = k - q * TN;   // 20%4==0: never spans q
            float4 v;
            v.x = -ben[t0 + 0][q]; v.y = -ben[t0 + 1][q];
            v.z = -ben[t0 + 2][q]; v.w = -ben[t0 + 3][q];
            dst[i] = v;
        }
    }

    // ---- benefit chunk -> registers: lane = t*3 + j, chunks q0 = 0/36/72 (16B-aligned) ----
    const int myt = lane / 3;                       // 20,21 for lanes 60..63 (spectators)
    const int jj  = lane - myt * 3;
    const int q0  = jj * 36;                        // scan reads up to 107 < BSTR
    const bool is_leader = (lane < 60) && (jj == 0);
    float4 breg4[9];
    {
        const int tt = (lane < 60) ? myt : 0;
        const float4* bp = reinterpret_cast<const float4*>(&ben[tt][q0]);
        #pragma unroll
        for (int k = 0; k < 9; ++k) breg4[k] = bp[k];
    }
    int myobj = -1;

    // per-leader cached top-2 state (exact while cval):
    //   cv0 = ben[ci0]-price[ci0] (current), cb0 = ben[ci0], cp0 = price[ci0],
    //   cv1 = exact second-max value, ci1 = an untouched achiever of cv1, cb1 = ben[ci1]
    float cv0 = 0.f, cv1 = 0.f, cb0 = 0.f, cb1 = 0.f, cp0 = 0.f;
    int ci0 = 0, ci1 = 0;
    bool cval = false;

    // ---- auction: Jacobi, exact reference dynamics, single-wave, ZERO barriers ----
    for (int it = 0; it < 20000; ++it) {
        unsigned long long U = __ballot(is_leader && (myobj < 0));   // bits at 3t
        if (U == 0ull) break;
        unsigned long long R = __ballot(is_leader && (myobj < 0) && !cval);

        if (R != 0ull) {
            // full 3-lane rescan for triples whose leader bit is in R
            const bool doscan = (lane < 60) && (((R >> (3 * myt)) & 1ull) != 0ull);
            float v0 = -INFINITY, v1 = -INFINITY, b0 = 0.f, b1 = 0.f;
            int i0 = q0, i1 = q0;
            if (doscan) {
                const float4* pp = reinterpret_cast<const float4*>(&price[q0]);
                #pragma unroll
                for (int k = 0; k < 9; ++k) {
                    float4 bv = breg4[k];
                    float4 pv = pp[k];                  // ds_read_b128
                    SCAN6(bv.x, pv.x, q0 + 4*k + 0);
                    SCAN6(bv.y, pv.y, q0 + 4*k + 1);
                    SCAN6(bv.z, pv.z, q0 + 4*k + 2);
                    SCAN6(bv.w, pv.w, q0 + 4*k + 3);
                }
            }
            // ordered 3-way merge via shuffles (all lanes execute; leaders consume)
            {
                float av0 = __shfl_down(v0, 1), av1 = __shfl_down(v1, 1);
                float ab0 = __shfl_down(b0, 1), ab1 = __shfl_down(b1, 1);
                int   ai0 = __shfl_down(i0, 1), ai1 = __shfl_down(i1, 1);
                float bv0 = __shfl_down(v0, 2), bv1 = __shfl_down(v1, 2);
                float bb0 = __shfl_down(b0, 2), bb1 = __shfl_down(b1, 2);
                int   bi0 = __shfl_down(i0, 2), bi1 = __shfl_down(i1, 2);
                MERGE6(av0, ai0, ab0, av1, ai1, ab1);
                MERGE6(bv0, bi0, bb0, bv1, bi1, bb1);
            }
            if (is_leader && (((R >> lane) & 1ull) != 0ull)) {
                cv0 = v0; ci0 = i0; cb0 = b0;
                cv1 = v1; ci1 = i1; cb1 = b1;
                cp0 = price[ci0];                       // exact current price at argmax
                cval = true;
            }
        }

        // bid from cache (active implies cval: R-pass just refreshed it)
        const bool active = is_leader && (myobj < 0);
        const int   mybidq = ci0;
        const float mybid  = cp0 + (cv0 - cv1) + eps;   // exact ref op order
        if (active) {
            bid2[myt] = ((unsigned long long)__float_as_uint(mybid) << 32) | (unsigned)mybidq;
        }

        // single LDS round-trip: resolution + eviction + cache maintenance in one pass
        if (is_leader) {
            bool lose = false, hit0 = false, kill = false, ev = false;
            float np0 = -INFINITY;                      // max bid on ci0 this round
            unsigned long long uu = U;
            while (uu) {
                int pos = (int)__builtin_ctzll(uu); uu &= uu - 1ull;
                int t2 = pos / 3;
                unsigned long long pk = bid2[t2];       // ds_read_b64
                int q2 = (int)(unsigned)(pk & 0xffffffffull);
                float f2 = __uint_as_float((unsigned)(pk >> 32));
                // resolution (self-compare is harmlessly false)
                lose = lose || (active && q2 == mybidq &&
                                (f2 > mybid || (f2 == mybid && t2 < myt)));
                // eviction: any bid on my object always displaces me (a winner always exists)
                ev = ev || (q2 == myobj);
                // cache maintenance: price[q] becomes max of bids on q
                bool h0 = (q2 == ci0);
                np0 = h0 ? fmaxf(np0, f2) : np0;
                hit0 = hit0 || h0;
                kill = kill || (q2 == ci1);
            }
            if (active && !lose) {                      // winners have distinct q
                myobj = mybidq;
                price[mybidq] = mybid;                  // winner bid == max bid, bit-exact
            } else if (ev) {
                myobj = -1;
            }
            if (cval) {
                if (hit0) { cp0 = np0; cv0 = cb0 - cp0; }   // single sub == rescan result
                // invalid if second-max contributor touched, or top-2 order no longer strict
                if (kill || (hit0 && !(cv0 > cv1))) cval = false;
            }
        }
    }
    __syncthreads();
    if (is_leader) objl[myt] = myobj;
    __syncthreads();

    // ---- stable argsort of obj_of (rank computation) ----
    if (lane < TN) {
        int v = objl[lane];
        int r = 0;
        for (int u2 = 0; u2 < TN; ++u2) {
            int w = objl[u2];
            r += (w < v) || (w == v && u2 < lane);
        }
        out_pred[(size_t)bf * TN + r] = (float)v;
        out_tgt[(size_t)bf * TN + r]  = (float)lane;
    }
}

extern "C" void kernel_launch(void* const* d_in, const int* in_sizes, int n_in,
                              void* d_out, int out_size, void* d_ws, size_t ws_size,
                              hipStream_t stream) {
    const float* logits  = (const float*)d_in[0];
    const float* pboxes  = (const float*)d_in[1];
    const int*   tlabels = (const int*)d_in[2];
    const float* tboxes  = (const float*)d_in[3];

    float* out = (float*)d_out;
    float* out_cost = out;                                   // 64*36*100*20
    float* out_pred = out + (size_t)NB * NF * QN * TN;       // 64*36*20
    float* out_tgt  = out_pred + (size_t)NB * NF * TN;       // 64*36*20

    hipLaunchKernelGGL(matcher_kernel, dim3(NB * NF), dim3(64), 0, stream,
                       logits, pboxes, tlabels, tboxes, out_cost, out_pred, out_tgt);
}